// Round 12
// baseline (237.576 us; speedup 1.0000x reference)
//
#include <hip/hip_runtime.h>
#include <cstddef>

// AttentionLayerPooler: out[m,n] = sum_l softmax(logits)[m,l] * in[l,n]
// LT=36, LS=28, slice = 2,097,152 fp32.
//
// R5-R11: six structurally different kernels (one-shot, pipelined,
// counted-vmcnt, SMEM weights, barrier-free single-wave, 8KB-contiguous
// runs) ALL land 229-245 us @ ~3.3 TB/s HBM-view. Disproven: LDS pipe,
// vmem drain, barriers, occupancy, run length. fillBuffer hits 6.9 TB/s
// at 11% occupancy on the same chip -> memory system wants FEW quasi-
// sequential streams, not more waves.
// R12 = R11 + XCD-aware bijective swizzle (T1). Default dispatch
// round-robins adjacent chunks across XCDs -> each XCD's L2-miss stream
// is random line-pieces over the full 8 MB layer span (DRAM page
// thrash). Swizzled: XCD x owns a contiguous 2 MB window per layer;
// ~64 resident blocks/XCD walk a ~512 KB moving window -> per-channel
// open-row count drops ~10x; 8 disjoint quasi-sequential miss streams.

constexpr int LT = 36;
constexpr int LS = 28;
constexpr int NELEM = 2097152;          // floats per layer slice
constexpr int CHUNK = 2048;             // floats per layer per block (8 KB)
constexpr int NCHUNK = NELEM / CHUNK;   // 1024 chunks per tensor
constexpr int TPB = 512;                // 8 waves; thread owns 4 floats
constexpr int NWG = 2 * NCHUNK;         // 2048 (divisible by 8 -> simple swizzle OK)
constexpr int W_TSTRIDE = LS * LT;      // 1008 floats per weight table

typedef __attribute__((ext_vector_type(4))) float f32x4;

// Pre-kernel: softmax both 28x36 tables into d_ws, layout ws[t][l][m]
// (m contiguous): layer l's 28 weights at byte offset t*4032 + l*112,
// 16B-aligned -> 7 s_load_dwordx4 per layer.
__global__ __launch_bounds__(64) void softmax_kernel(
    const float* __restrict__ lgk, const float* __restrict__ lgv,
    float* __restrict__ ws)
{
    const int t = threadIdx.x;
    const int isv = t >> 5;
    const int m = t & 31;
    if (m >= LS) return;
    const float* row = (isv ? lgv : lgk) + m * LT;
    float mx = -3.4e38f;
    for (int l = 0; l < LT; ++l) mx = fmaxf(mx, row[l]);
    float s = 0.f;
    for (int l = 0; l < LT; ++l) s += expf(row[l] - mx);
    const float inv = 1.0f / s;
    float* o = ws + isv * W_TSTRIDE;
    for (int l = 0; l < LT; ++l) o[l * LS + m] = expf(row[l] - mx) * inv;
}

// One layer: 7 weight quads via SMEM (28 SGPRs, K$-hot), 112 FMAs.
__device__ __forceinline__ void layer_fma(const float* wlp, const float4 dv,
                                          float4* acc)
{
    f32x4 w0, w1, w2, w3, w4, w5, w6;
    asm volatile(
        "s_load_dwordx4 %0, %[b], %[o0]\n\t"
        "s_load_dwordx4 %1, %[b], %[o1]\n\t"
        "s_load_dwordx4 %2, %[b], %[o2]\n\t"
        "s_load_dwordx4 %3, %[b], %[o3]\n\t"
        "s_load_dwordx4 %4, %[b], %[o4]\n\t"
        "s_load_dwordx4 %5, %[b], %[o5]\n\t"
        "s_load_dwordx4 %6, %[b], %[o6]\n\t"
        "s_waitcnt lgkmcnt(0)"
        : "=s"(w0), "=s"(w1), "=s"(w2), "=s"(w3), "=s"(w4), "=s"(w5), "=s"(w6)
        : [b] "s"(wlp),
          [o0] "i"(0),  [o1] "i"(16), [o2] "i"(32), [o3] "i"(48),
          [o4] "i"(64), [o5] "i"(80), [o6] "i"(96));

    const f32x4 W[7] = {w0, w1, w2, w3, w4, w5, w6};
#pragma unroll
    for (int q = 0; q < 7; ++q) {
#pragma unroll
        for (int j = 0; j < 4; ++j) {
            const float w = W[q][j];
            float4& a = acc[4 * q + j];
            a.x = fmaf(w, dv.x, a.x);
            a.y = fmaf(w, dv.y, a.y);
            a.z = fmaf(w, dv.z, a.z);
            a.w = fmaf(w, dv.w, a.w);
        }
    }
}

__global__ __launch_bounds__(TPB) void pool_kernel(
    const float* __restrict__ ks,
    const float* __restrict__ vs,
    const float* __restrict__ ws,
    float* __restrict__ out)
{
    // Depth-3 rotation of 8 KB layer-chunks = 24 KB. Each wave DMAs and
    // reads ONLY its own 1 KB segment -> no cross-wave deps, no barriers.
    __shared__ float buf[3][CHUNK];

    const int tid  = threadIdx.x;
    const int wv   = tid >> 6;

    // T1: bijective XCD swizzle (NWG % 8 == 0). Dispatch round-robins
    // blockIdx over 8 XCDs; remap so XCD x gets a CONTIGUOUS run of
    // chunk ids -> per-XCD quasi-sequential L2-miss stream.
    const int bid = ((int)blockIdx.x & 7) * (NWG / 8) + ((int)blockIdx.x >> 3);

    const bool isv = (bid >= NCHUNK);
    const float* src = isv ? vs : ks;
    const float* wl0 = ws + (isv ? W_TSTRIDE : 0);
    float* dstb = out + (isv ? (size_t)LS * NELEM : (size_t)0);
    const size_t cbase = (size_t)(bid & (NCHUNK - 1)) * CHUNK;
    const size_t toff  = cbase + (size_t)tid * 4;  // thread's 16 B in the run

    // Stage layer l's 8 KB contiguous run: ONE global_load_lds per wave.
    auto stage = [&](int d, int l) {
        const float* g = src + (size_t)l * NELEM + toff;
        __builtin_amdgcn_global_load_lds(
            (const __attribute__((address_space(1))) void*)g,
            (__attribute__((address_space(3))) void*)&buf[d][wv * 256],
            16, 0, 0);
    };

    stage(0, 0);
    stage(1, 1);

    float4 acc[LS];
#pragma unroll
    for (int m = 0; m < LS; ++m) acc[m] = make_float4(0.f, 0.f, 0.f, 0.f);

    // Main loop: issue load(l+2), wait for load(l) only (vmcnt(2): loads
    // l+1, l+2 stay in flight). Slot reuse safe: slot (l+2)%3 was read at
    // iter l-1, drained by layer_fma's lgkmcnt(0).
    for (int l = 0; l < LT - 2; ++l) {
        stage((l + 2) % 3, l + 2);
        asm volatile("s_waitcnt vmcnt(2)" ::: "memory");
        __builtin_amdgcn_sched_barrier(0);
        const float4 dv = *reinterpret_cast<const float4*>(&buf[l % 3][tid * 4]);
        layer_fma(wl0 + l * LS, dv, acc);
    }
    asm volatile("s_waitcnt vmcnt(1)" ::: "memory");
    __builtin_amdgcn_sched_barrier(0);
    {
        const float4 dv = *reinterpret_cast<const float4*>(&buf[(LT - 2) % 3][tid * 4]);
        layer_fma(wl0 + (LT - 2) * LS, dv, acc);
    }
    asm volatile("s_waitcnt vmcnt(0)" ::: "memory");
    __builtin_amdgcn_sched_barrier(0);
    {
        const float4 dv = *reinterpret_cast<const float4*>(&buf[(LT - 1) % 3][tid * 4]);
        layer_fma(wl0 + (LT - 1) * LS, dv, acc);
    }

    // 28 output streams, each one 8 KB contiguous run (dwordx4/lane).
#pragma unroll
    for (int m = 0; m < LS; ++m) {
        float4* q = reinterpret_cast<float4*>(dstb + (size_t)m * NELEM + cbase);
        q[tid] = acc[m];
    }
}

extern "C" void kernel_launch(void* const* d_in, const int* in_sizes, int n_in,
                              void* d_out, int out_size, void* d_ws, size_t ws_size,
                              hipStream_t stream)
{
    const float* ks  = (const float*)d_in[0];
    const float* vs  = (const float*)d_in[1];
    const float* lgk = (const float*)d_in[2];
    const float* lgv = (const float*)d_in[3];
    float* ws  = (float*)d_ws;     // 8064 B scratch for softmaxed weights
    float* out = (float*)d_out;

    hipLaunchKernelGGL(softmax_kernel, dim3(1), dim3(64), 0, stream,
                       lgk, lgv, ws);
    hipLaunchKernelGGL(pool_kernel, dim3(NWG), dim3(TPB), 0, stream,
                       ks, vs, ws, out);
}